// Round 8
// baseline (228.659 us; speedup 1.0000x reference)
//
#include <hip/hip_runtime.h>
#include <hip/hip_bf16.h>
#include <stdint.h>

#define M_DIM 8192
#define K_DIM 4096
#define N_DIM 4096

#define BM 256
#define BN 128
#define BKB 64              // K-bytes (=i8 elems) per tile
#define NT (K_DIM / BKB)    // 64 K-tiles
#define ATILE (BM * BKB)    // 16384 B
#define BTILE (BN * BKB)    // 8192 B
#define TBYTES (ATILE + BTILE)      // 24576 B per K-tile buffer

typedef int i32x4 __attribute__((ext_vector_type(4)));

// ---------------------------------------------------------------------------
// Kernel 1: per-tensor activation quantization f32 -> i8 (unchanged, passing)
// ---------------------------------------------------------------------------
__global__ __launch_bounds__(256) void quant_x_kernel(
    const float* __restrict__ x, const float* __restrict__ scale_p,
    const int* __restrict__ off_p, int8_t* __restrict__ xq)
{
    const float s = scale_p[0];
    const float off = (float)off_p[0];
    long base = ((long)blockIdx.x * 256 + threadIdx.x) * 16;
    const float4* xin = (const float4*)(x + base);
    float v[16];
    *(float4*)(v + 0)  = xin[0];
    *(float4*)(v + 4)  = xin[1];
    *(float4*)(v + 8)  = xin[2];
    *(float4*)(v + 12) = xin[3];
    uint32_t pk[4];
#pragma unroll
    for (int g = 0; g < 4; ++g) {
        uint32_t p = 0;
#pragma unroll
        for (int j = 0; j < 4; ++j) {
            float q = rintf(v[g * 4 + j] / s) + off;
            q = fminf(fmaxf(q, -128.0f), 127.0f);
            int qi = (int)q;
            p |= ((uint32_t)(qi & 0xff)) << (8 * j);
        }
        pk[g] = p;
    }
    uint4 o; o.x = pk[0]; o.y = pk[1]; o.z = pk[2]; o.w = pk[3];
    *(uint4*)(xq + base) = o;
}

// ---------------------------------------------------------------------------
// Kernel 2: weight pack + permutation fold (unchanged, passing)
// ---------------------------------------------------------------------------
__global__ __launch_bounds__(256) void pack_w_kernel(
    const int* __restrict__ w, const int* __restrict__ index,
    const float* __restrict__ deq, const int* __restrict__ qb,
    int8_t* __restrict__ bp, float* __restrict__ dsp, int* __restrict__ qbp)
{
    int j = blockIdx.x;
    int t = threadIdx.x;
    int src = index[j];
    const int4* wrow = (const int4*)(w + (long)src * K_DIM);
    uint32_t pk[4];
#pragma unroll
    for (int g = 0; g < 4; ++g) {
        int4 c = wrow[t * 4 + g];
        pk[g] = ((uint32_t)(c.x & 0xff)) | (((uint32_t)(c.y & 0xff)) << 8) |
                (((uint32_t)(c.z & 0xff)) << 16) | (((uint32_t)(c.w & 0xff)) << 24);
    }
    uint4 o; o.x = pk[0]; o.y = pk[1]; o.z = pk[2]; o.w = pk[3];
    *(uint4*)(bp + (long)j * K_DIM + t * 16) = o;
    if (t == 0) { dsp[j] = deq[src]; qbp[j] = qb[src]; }
}

// ---------------------------------------------------------------------------
// Kernel 3: 256x128 int8 GEMM, 4 waves/block, ring-3 24KB buffers = 72KB
// LDS -> TWO blocks resident per CU. Same per-wave work and schedule as R3
// (the best variant): per K-tile {12 ds_read_b128 -> 6 global_load_lds of
// t+2 -> 32 MFMA, compiler-scheduled} -> lgkmcnt(0) -> vmcnt(6) -> barrier.
// R2-R7 diagnosis: with one 8-wave block per CU, every barrier drains the
// whole CU -> MFMA and DS pipes serialize (counters additive). Two
// independent blocks per CU give uncorrelated barrier phases: block A's
// drain overlaps block B's MFMA burst (m114 mechanism).
// ---------------------------------------------------------------------------
__device__ __forceinline__ void gload_lds16(const int8_t* g, int8_t* l)
{
    __builtin_amdgcn_global_load_lds(
        (const __attribute__((address_space(1))) uint32_t*)g,
        (__attribute__((address_space(3))) uint32_t*)l, 16, 0, 0);
}

__global__ __launch_bounds__(256, 2) void gemm_i8_kernel(
    const int8_t* __restrict__ A, const int8_t* __restrict__ B,
    const float* __restrict__ dsp, const int* __restrict__ qbp,
    float* __restrict__ C)
{
    __shared__ int8_t tb0[TBYTES];   // ring slot 0 (A | B halves)
    __shared__ int8_t tb1[TBYTES];   // ring slot 1
    __shared__ int8_t tb2[TBYTES];   // ring slot 2   -> 72 KB total

    // XCD-aware bijective swizzle (grid = 1024, divisible by 8).
    // bm-fast within an XCD chunk: the 4 hot B-panels (4 x 512KB) stay in
    // that XCD's L2 while bm sweeps.
    int bid = blockIdx.x;
    int swz = (bid & 7) * (gridDim.x >> 3) + (bid >> 3);
    int bm = swz & 31;              // M/BM = 32
    int bn = swz >> 5;              // N/BN = 32
    int brow = bm * BM, bcol = bn * BN;

    int t = threadIdx.x;
    int wv = t >> 6;                // 4 waves
    int l  = t & 63;
    int lr = l & 15;                // row within 16x16 fragment
    int ls = l >> 4;                // logical 16B k-slot
    int wrM = (wv >> 1) * 128;      // wave row offset (2 M-waves)
    int wcN = (wv & 1) * 64;        // wave col offset (2 N-waves)
    int pslot = ls ^ ((lr >> 1) & 3);   // swizzled physical slot (lane-const)

    // ds_read byte offsets within a K-tile buffer (A half then B half)
    int aoff[8], boff[4];
#pragma unroll
    for (int m = 0; m < 8; ++m)
        aoff[m] = (wrM + m * 16 + lr) * BKB + pslot * 16;
#pragma unroll
    for (int n = 0; n < 4; ++n)
        boff[n] = ATILE + (wcN + n * 16 + lr) * BKB + pslot * 16;

    // Staging: per thread 4 A-chunks + 2 B-chunks (16B each) per K-tile.
    // Linear LDS dest; global source pre-swizzled (slot = (c&3)^((row>>1)&3)).
    const int8_t* sa[4]; int da[4];
    const int8_t* sb[2]; int db[2];
#pragma unroll
    for (int i = 0; i < 4; ++i) {
        int ca = i * 256 + t;
        int row = ca >> 2;
        int lg = (ca & 3) ^ ((row >> 1) & 3);
        sa[i] = A + (long)(brow + row) * K_DIM + lg * 16;
        da[i] = ca * 16;
    }
#pragma unroll
    for (int i = 0; i < 2; ++i) {
        int cb = i * 256 + t;
        int row = cb >> 2;
        int lg = (cb & 3) ^ ((row >> 1) & 3);
        sb[i] = B + (long)(bcol + row) * K_DIM + lg * 16;
        db[i] = ATILE + cb * 16;
    }

#define STAGE6(STG) do { \
        gload_lds16(sa[0], (STG) + da[0]); \
        gload_lds16(sa[1], (STG) + da[1]); \
        gload_lds16(sa[2], (STG) + da[2]); \
        gload_lds16(sa[3], (STG) + da[3]); \
        gload_lds16(sb[0], (STG) + db[0]); \
        gload_lds16(sb[1], (STG) + db[1]); \
        sa[0] += BKB; sa[1] += BKB; sa[2] += BKB; sa[3] += BKB; \
        sb[0] += BKB; sb[1] += BKB; \
    } while (0)

// One K-tile: frag reads from CUR, prefetch t+2 into STG, MFMA cluster with
// compiler-counted lgkm interleave, tile-end lgkm0 (buffer-reuse invariant)
// + counted vmcnt + raw barrier.
#define GEMM_TILE(CUR, STG, KT) do { \
        i32x4 af[8], bf[4]; \
        _Pragma("unroll") \
        for (int n = 0; n < 4; ++n) bf[n] = *(const i32x4*)((CUR) + boff[n]); \
        _Pragma("unroll") \
        for (int m = 0; m < 8; ++m) af[m] = *(const i32x4*)((CUR) + aoff[m]); \
        const bool _st = (KT) + 2 < NT; \
        if (_st) STAGE6(STG); \
        _Pragma("unroll") \
        for (int m = 0; m < 8; ++m) \
        _Pragma("unroll") \
        for (int n = 0; n < 4; ++n) \
            acc[m][n] = __builtin_amdgcn_mfma_i32_16x16x64_i8( \
                af[m], bf[n], acc[m][n], 0, 0, 0); \
        asm volatile("s_waitcnt lgkmcnt(0)" ::: "memory"); \
        if (_st) asm volatile("s_waitcnt vmcnt(6)" ::: "memory"); \
        else     asm volatile("s_waitcnt vmcnt(0)" ::: "memory"); \
        __builtin_amdgcn_s_barrier(); \
    } while (0)

    // Prologue: stage tiles 0 -> tb0, 1 -> tb1
    STAGE6(tb0);
    STAGE6(tb1);
    asm volatile("s_waitcnt vmcnt(6)" ::: "memory");   // tile 0 resident
    __builtin_amdgcn_s_barrier();

    i32x4 acc[8][4] = {};

    // Main loop: 63 tiles = 21 iterations x ring period 3; tail tile 63.
    for (int kt = 0; kt < 63; kt += 3) {
        GEMM_TILE(tb0, tb2, kt);
        GEMM_TILE(tb1, tb0, kt + 1);
        GEMM_TILE(tb2, tb1, kt + 2);
    }
    // Tail tile 63 (cur = tb0, no stage, no trailing barrier needed)
    {
        i32x4 af[8], bf[4];
#pragma unroll
        for (int n = 0; n < 4; ++n) bf[n] = *(const i32x4*)(tb0 + boff[n]);
#pragma unroll
        for (int m = 0; m < 8; ++m) af[m] = *(const i32x4*)(tb0 + aoff[m]);
#pragma unroll
        for (int m = 0; m < 8; ++m)
#pragma unroll
            for (int n = 0; n < 4; ++n)
                acc[m][n] = __builtin_amdgcn_mfma_i32_16x16x64_i8(
                    af[m], bf[n], acc[m][n], 0, 0, 0);
    }

#undef STAGE6
#undef GEMM_TILE

    // Epilogue: C/D layout col = lane&15, row = (lane>>4)*4 + reg
#pragma unroll
    for (int n = 0; n < 4; ++n) {
        int gc = bcol + wcN + n * 16 + lr;
        float ds = dsp[gc];
        int qb = qbp[gc];
#pragma unroll
        for (int m = 0; m < 8; ++m) {
            int gr0 = brow + wrM + m * 16 + ls * 4;
#pragma unroll
            for (int r = 0; r < 4; ++r) {
                C[(long)(gr0 + r) * N_DIM + gc] = (float)(acc[m][n][r] + qb) * ds;
            }
        }
    }
}

// ---------------------------------------------------------------------------
extern "C" void kernel_launch(void* const* d_in, const int* in_sizes, int n_in,
                              void* d_out, int out_size, void* d_ws, size_t ws_size,
                              hipStream_t stream)
{
    (void)in_sizes; (void)n_in; (void)out_size; (void)ws_size;
    const float* x   = (const float*)d_in[0];
    const int*   w   = (const int*)d_in[1];
    const float* is  = (const float*)d_in[2];
    const int*   io  = (const int*)d_in[3];
    const float* dq  = (const float*)d_in[4];
    const int*   qb  = (const int*)d_in[5];
    const int*   idx = (const int*)d_in[6];
    float* out = (float*)d_out;

    int8_t* xq  = (int8_t*)d_ws;                           // 33554432 B
    int8_t* bp  = xq + (size_t)M_DIM * K_DIM;              // 16777216 B
    float*  dsp = (float*)(bp + (size_t)N_DIM * K_DIM);    // 16384 B
    int*    qbp = (int*)(dsp + N_DIM);                     // 16384 B

    long quant_blocks = ((long)M_DIM * K_DIM) / 16 / 256;  // 8192
    quant_x_kernel<<<(int)quant_blocks, 256, 0, stream>>>(x, is, io, xq);
    pack_w_kernel<<<N_DIM, 256, 0, stream>>>(w, idx, dq, qb, bp, dsp, qbp);
    gemm_i8_kernel<<<(M_DIM / BM) * (N_DIM / BN), 256, 0, stream>>>(xq, bp, dsp, qbp, out);
}